// Round 17
// baseline (208.582 us; speedup 1.0000x reference)
//
#include <hip/hip_runtime.h>
#include <hip/hip_bf16.h>
#include <cmath>

// SSIM loss via MFMA, round 17: ONE-WAVE BLOCKS (TLP, not ILP).
// H pass: 16x16x32 bf16 MFMA (A=data rows, B=banded Gaussian W).
// H's D-layout (lane: rows 4g+i, col m) IS the B-frag layout of a K=16 MFMA
// (lane: k=4g+j, col m), so V = 2 chained mfma_16x16x16_bf16 per quantity with
// B-frags straight from H result registers. No hq LDS staging.
// vs rounds 13-16 (44.7-49.5us plateau; every intra-wave scheduling lever
// flat): waves are fully independent, so drop the 256-thread block envelope.
// Block = 64 threads = 1 wave, grid = 8192; __launch_bounds__(64,8) targets
// 8 waves/SIMD. Blocks schedule/retire individually -> real occupancy.
// Pipeline inside the wave is round-13's 3-phase rotation (best known).

#define IMG   512
#define ODIM  502            // 512 - 11 + 1
#define SC    16             // strip cols (per wave/block)
#define BR    128            // strip rows
#define GX    32             // 512/16
#define GY    4              // 512/128
#define NC    64             // batch*channels
#define NBLK  (GX * GY * NC) // 8192

typedef float          f32x4  __attribute__((ext_vector_type(4)));
typedef __bf16         bf16x8 __attribute__((ext_vector_type(8)));
typedef __bf16         bf16x4 __attribute__((ext_vector_type(4)));
typedef short          s16x4  __attribute__((ext_vector_type(4)));
typedef unsigned int   u32x2  __attribute__((ext_vector_type(2)));
typedef unsigned int   u32x4  __attribute__((ext_vector_type(4)));

union F8 { bf16x8 v; __bf16 b[8]; u32x4 q; };
union F4 { bf16x4 v; s16x4 s; __bf16 b[4]; u32x2 q; };

__device__ __forceinline__ unsigned short bfbits(float f) {
    __bf16 h = (__bf16)f;
    return __builtin_bit_cast(unsigned short, h);
}

__device__ __forceinline__ f32x4 mfma16(const F4& a, const F4& b, f32x4 c) {
    return __builtin_amdgcn_mfma_f32_16x16x16bf16_1k(a.s, b.s, c, 0, 0, 0);
}

struct GaussW { float g[11]; };

__global__ __launch_bounds__(64, 8) void ssim_mfma_kernel(
    const float* __restrict__ X, const float* __restrict__ Y,
    float* __restrict__ partial, GaussW gw)
{
    __shared__ unsigned short wl[16][40];   // band weights: wl[m][k] = w[k-m]

    const int lane = threadIdx.x;           // one wave per block
    const int m    = lane & 15;
    const int g    = lane >> 4;

    // ---- weight band LUT (filled by this wave; in-wave visibility only) ----
    for (int t = lane; t < 16 * 40; t += 64) {
        const int mm = t / 40, kk = t - 40 * mm;
        const int d  = kk - mm;
        wl[mm][kk] = bfbits((kk < 32 && d >= 0 && d < 11) ? gw.g[d] : 0.f);
    }
    __syncthreads();                        // wave-local: cheap

    const int gx0 = blockIdx.x * SC;        // this wave's strip
    const int gy0 = blockIdx.y * BR;
    const int nc  = blockIdx.z;
    const float* __restrict__ Xp = X + (size_t)nc * IMG * IMG;
    const float* __restrict__ Yp = Y + (size_t)nc * IMG * IMG;

    F8 wf;  wf.q  = *(const u32x4*)&wl[m][8 * g];       // H B-frag: w[8g+j - m]
    F4 wa0; wa0.q = *(const u32x2*)&wl[m][4 * g];       // V A chunk0: w[4g+j - m]
    F4 wa1; wa1.q = *(const u32x2*)&wl[m][16 + 4 * g];  // V A chunk1: w[16+4g+j - m]
    const f32x4 z = {0.f, 0.f, 0.f, 0.f};

    const int cs = min(gx0 + 8 * g, IMG - 8);   // clamped cols feed only masked
                                                // outputs (band is zero there)
    const float* __restrict__ xbase = Xp + (gy0 + m) * IMG + cs;
    const float* __restrict__ ybase = Yp + (gy0 + m) * IMG + cs;

    // H stage from by-value raw regs; squares via f32x4 vector ops (pk_mul)
    auto mfmaH = [&](F4 (&hd)[5], f32x4 a0, f32x4 a1, f32x4 b0, f32x4 b1) {
        const f32x4 xx0 = a0 * a0, xx1 = a1 * a1;
        const f32x4 yy0 = b0 * b0, yy1 = b1 * b1;
        const f32x4 xy0 = a0 * b0, xy1 = a1 * b1;
        F8 fx, fy, fxx, fyy, fxy;
#pragma unroll
        for (int j = 0; j < 4; ++j) {
            fx.b[j]      = (__bf16)a0[j];
            fx.b[4 + j]  = (__bf16)a1[j];
            fy.b[j]      = (__bf16)b0[j];
            fy.b[4 + j]  = (__bf16)b1[j];
            fxx.b[j]     = (__bf16)xx0[j];
            fxx.b[4 + j] = (__bf16)xx1[j];
            fyy.b[j]     = (__bf16)yy0[j];
            fyy.b[4 + j] = (__bf16)yy1[j];
            fxy.b[j]     = (__bf16)xy0[j];
            fxy.b[4 + j] = (__bf16)xy1[j];
        }
        const f32x4 dX  = __builtin_amdgcn_mfma_f32_16x16x32_bf16(fx.v,  wf.v, z, 0, 0, 0);
        const f32x4 dY  = __builtin_amdgcn_mfma_f32_16x16x32_bf16(fy.v,  wf.v, z, 0, 0, 0);
        const f32x4 dXX = __builtin_amdgcn_mfma_f32_16x16x32_bf16(fxx.v, wf.v, z, 0, 0, 0);
        const f32x4 dYY = __builtin_amdgcn_mfma_f32_16x16x32_bf16(fyy.v, wf.v, z, 0, 0, 0);
        const f32x4 dXY = __builtin_amdgcn_mfma_f32_16x16x32_bf16(fxy.v, wf.v, z, 0, 0, 0);
#pragma unroll
        for (int i = 0; i < 4; ++i) {
            hd[0].b[i] = (__bf16)dX[i];
            hd[1].b[i] = (__bf16)dY[i];
            hd[2].b[i] = (__bf16)dXX[i];
            hd[3].b[i] = (__bf16)dYY[i];
            hd[4].b[i] = (__bf16)dXY[i];
        }
    };

    f32x4 vacc = z;                       // packed accumulator (fixed order)
    const int gxv   = gx0 + m;            // this lane's output col
    const bool colok = (gxv < ODIM);

    // V stage + vectorized SSIM epilogue for output tile vt (literal)
    auto vstage = [&](const F4 (&h0)[5], const F4 (&h1)[5], int vt) {
        f32x4 e[5];
#pragma unroll
        for (int q = 0; q < 5; ++q) {
            e[q] = mfma16(wa1, h1[q], z);
            e[q] = mfma16(wa0, h0[q], e[q]);
        }
        const float C1 = 1e-4f, C2 = 9e-4f;
        const f32x4 mX = e[0], mY = e[1];
        const f32x4 muXX = mX * mX;
        const f32x4 muYY = mY * mY;
        const f32x4 muXY = mX * mY;
        const f32x4 sXX = e[2] - muXX;
        const f32x4 sYY = e[3] - muYY;
        const f32x4 sXY = e[4] - muXY;
        const f32x4 num = (2.f * muXY + C1) * (2.f * sXY + C2);
        const f32x4 den = (muXX + muYY + C1) * (sXX + sYY + C2);
        f32x4 val;
#pragma unroll
        for (int i = 0; i < 4; ++i) val[i] = __fdividef(num[i], den[i]);
        const int gyb = gy0 + 16 * vt + 4 * g;   // rows gyb..gyb+3
#pragma unroll
        for (int i = 0; i < 4; ++i)
            vacc[i] += (colok && (gyb + i < ODIM)) ? val[i] : 0.f;
    };

    // ---- 3-phase pipeline: named raw trios A/B/C, h slots h0/h1/h2 ----
    f32x4 xA0, xA1, yA0, yA1;
    f32x4 xB0, xB1, yB0, yB1;
    f32x4 xC0, xC1, yC0, yC1;
    F4 h0[5], h1[5], h2[5];

    // tiles 0..7 never clamp (max gy = 384+112+15 = 511); tile 8 clamps.
#define LOADRAW(rt, X0, X1, Y0, Y1) do {                                   \
        const float* xr_;  const float* yr_;                               \
        if ((rt) < 8) {                                                    \
            xr_ = xbase + (rt) * 16 * IMG;                                 \
            yr_ = ybase + (rt) * 16 * IMG;                                 \
        } else {                                                           \
            const int gy_ = min(gy0 + 16 * (rt) + m, IMG - 1);             \
            xr_ = Xp + gy_ * IMG + cs;                                     \
            yr_ = Yp + gy_ * IMG + cs;                                     \
        }                                                                  \
        X0 = *(const f32x4*)xr_;  X1 = *(const f32x4*)(xr_ + 4);           \
        Y0 = *(const f32x4*)yr_;  Y1 = *(const f32x4*)(yr_ + 4);           \
    } while (0)

    // prologue: 3 tile-loads in flight, then H(0), H(1)
    LOADRAW(0, xA0, xA1, yA0, yA1);
    LOADRAW(1, xB0, xB1, yB0, yB1);
    LOADRAW(2, xC0, xC1, yC0, yC1);
    mfmaH(h0, xA0, xA1, yA0, yA1);          // tile 0 -> slot 0
    mfmaH(h1, xB0, xB1, yB0, yB1);          // tile 1 -> slot 1

    // step t: L(t+3) | H(t+2) | V(t).  tile k lives in raw/h slot k%3.
    LOADRAW(3, xA0, xA1, yA0, yA1);  mfmaH(h2, xC0, xC1, yC0, yC1);  vstage(h0, h1, 0);
    LOADRAW(4, xB0, xB1, yB0, yB1);  mfmaH(h0, xA0, xA1, yA0, yA1);  vstage(h1, h2, 1);
    LOADRAW(5, xC0, xC1, yC0, yC1);  mfmaH(h1, xB0, xB1, yB0, yB1);  vstage(h2, h0, 2);
    LOADRAW(6, xA0, xA1, yA0, yA1);  mfmaH(h2, xC0, xC1, yC0, yC1);  vstage(h0, h1, 3);
    LOADRAW(7, xB0, xB1, yB0, yB1);  mfmaH(h0, xA0, xA1, yA0, yA1);  vstage(h1, h2, 4);
    LOADRAW(8, xC0, xC1, yC0, yC1);  mfmaH(h1, xB0, xB1, yB0, yB1);  vstage(h2, h0, 5);
                                     mfmaH(h2, xC0, xC1, yC0, yC1);  vstage(h0, h1, 6);
                                                                     vstage(h1, h2, 7);
#undef LOADRAW

    // ---- deterministic reductions: vec4 -> lane -> wave ----
    float acc = (vacc[0] + vacc[1]) + (vacc[2] + vacc[3]);
#pragma unroll
    for (int off = 32; off > 0; off >>= 1)
        acc += __shfl_down(acc, off, 64);

    if (lane == 0) {
        partial[((size_t)blockIdx.z * gridDim.y + blockIdx.y) * gridDim.x + blockIdx.x] = acc;
    }
}

__global__ __launch_bounds__(512) void ssim_finish_kernel(
    const float* __restrict__ partial, float* __restrict__ out)
{
    __shared__ double sd[512];
    const float4* p4 = (const float4*)partial;   // NBLK = 8192 = 512*4*4
    double local = 0.0;
#pragma unroll
    for (int i = 0; i < 4; ++i) {
        const float4 v = p4[threadIdx.x + 512 * i];
        local += ((double)v.x + (double)v.y) + ((double)v.z + (double)v.w);
    }
    sd[threadIdx.x] = local;
    __syncthreads();
    for (int s = 256; s > 0; s >>= 1) {
        if (threadIdx.x < s) sd[threadIdx.x] += sd[threadIdx.x + s];
        __syncthreads();
    }
    if (threadIdx.x == 0) {
        const double cnt = (double)NC * (double)ODIM * (double)ODIM;
        out[0] = (float)(1.0 - sd[0] / cnt);
    }
}

extern "C" void kernel_launch(void* const* d_in, const int* in_sizes, int n_in,
                              void* d_out, int out_size, void* d_ws, size_t ws_size,
                              hipStream_t stream) {
    const float* X = (const float*)d_in[0];
    const float* Y = (const float*)d_in[1];
    float* out = (float*)d_out;
    float* partial = (float*)d_ws;   // NBLK floats = 32 KiB

    // Gaussian taps in float64 -> f32 (matches numpy reference construction).
    GaussW gw;
    {
        double gd[11], s = 0.0;
        for (int i = 0; i < 11; ++i) {
            const double x = (double)(i - 5);
            gd[i] = std::exp(-(x * x) / (2.0 * 1.5 * 1.5));
            s += gd[i];
        }
        for (int i = 0; i < 11; ++i) gw.g[i] = (float)(gd[i] / s);
    }

    dim3 grid(GX, GY, NC);
    ssim_mfma_kernel<<<grid, 64, 0, stream>>>(X, Y, partial, gw);
    ssim_finish_kernel<<<1, 512, 0, stream>>>(partial, out);
}

// Round 18
// 161.648 us; speedup vs baseline: 1.2903x; 1.2903x over previous
//
#include <hip/hip_runtime.h>
#include <hip/hip_bf16.h>
#include <cmath>

// SSIM loss via MFMA, round 18: 1-wave blocks + SHALLOW (live-2) pipeline.
// H pass: 16x16x32 bf16 MFMA (A=data rows, B=banded Gaussian W).
// H's D-layout (lane: rows 4g+i, col m) IS the B-frag layout of a K=16 MFMA
// (lane: k=4g+j, col m), so V = 2 chained mfma_16x16x16_bf16 per quantity with
// B-frags straight from H result registers. No hq LDS staging.
// Round-17 post-mortem: 1-wave blocks DID raise occupancy to 73% (TLP theory
// confirmed) but the 3-buffer pipeline needs ~95 VGPR > the (64,8) cap of 64
// -> spills (WRITE 342MB, 208us). Fix: round-8's live-2 structure (40 VGPR at
// 256-thread) under the same cap. TLP (8 waves/SIMD) covers latency; r12
// proved VALU issue count is not the limiter, so the shallow pipeline is fine.

#define IMG   512
#define ODIM  502            // 512 - 11 + 1
#define SC    16             // strip cols (per wave/block)
#define BR    128            // strip rows
#define GX    32             // 512/16
#define GY    4              // 512/128
#define NC    64             // batch*channels
#define NBLK  (GX * GY * NC) // 8192
#define NVT   8              // V tiles per strip
#define NHT   9              // H tiles per strip

typedef float          f32x4  __attribute__((ext_vector_type(4)));
typedef __bf16         bf16x8 __attribute__((ext_vector_type(8)));
typedef __bf16         bf16x4 __attribute__((ext_vector_type(4)));
typedef short          s16x4  __attribute__((ext_vector_type(4)));
typedef unsigned int   u32x2  __attribute__((ext_vector_type(2)));
typedef unsigned int   u32x4  __attribute__((ext_vector_type(4)));

union F8 { bf16x8 v; __bf16 b[8]; u32x4 q; };
union F4 { bf16x4 v; s16x4 s; __bf16 b[4]; u32x2 q; };

__device__ __forceinline__ unsigned short bfbits(float f) {
    __bf16 h = (__bf16)f;
    return __builtin_bit_cast(unsigned short, h);
}

__device__ __forceinline__ f32x4 mfma16(const F4& a, const F4& b, f32x4 c) {
    return __builtin_amdgcn_mfma_f32_16x16x16bf16_1k(a.s, b.s, c, 0, 0, 0);
}

struct GaussW { float g[11]; };

__global__ __launch_bounds__(64, 8) void ssim_mfma_kernel(
    const float* __restrict__ X, const float* __restrict__ Y,
    float* __restrict__ partial, GaussW gw)
{
    __shared__ unsigned short wl[16][40];   // band weights: wl[m][k] = w[k-m]

    const int lane = threadIdx.x;           // one wave per block
    const int m    = lane & 15;
    const int g    = lane >> 4;

    // ---- weight band LUT (filled by this wave) ----
    for (int t = lane; t < 16 * 40; t += 64) {
        const int mm = t / 40, kk = t - 40 * mm;
        const int d  = kk - mm;
        wl[mm][kk] = bfbits((kk < 32 && d >= 0 && d < 11) ? gw.g[d] : 0.f);
    }
    __syncthreads();                        // wave-local: cheap

    const int gx0 = blockIdx.x * SC;        // this wave's strip
    const int gy0 = blockIdx.y * BR;
    const int nc  = blockIdx.z;
    const float* __restrict__ Xp = X + (size_t)nc * IMG * IMG;
    const float* __restrict__ Yp = Y + (size_t)nc * IMG * IMG;

    F8 wf;  wf.q  = *(const u32x4*)&wl[m][8 * g];       // H B-frag: w[8g+j - m]
    F4 wa0; wa0.q = *(const u32x2*)&wl[m][4 * g];       // V A chunk0: w[4g+j - m]
    F4 wa1; wa1.q = *(const u32x2*)&wl[m][16 + 4 * g];  // V A chunk1: w[16+4g+j - m]
    const f32x4 z = {0.f, 0.f, 0.f, 0.f};

    const int cs = min(gx0 + 8 * g, IMG - 8);   // clamped cols feed only masked
                                                // outputs (band is zero there)
    const float* __restrict__ xbase = Xp + (gy0 + m) * IMG + cs;
    const float* __restrict__ ybase = Yp + (gy0 + m) * IMG + cs;

    // H stage from by-value raw regs; squares via f32x4 vector ops
    auto mfmaH = [&](F4 (&hd)[5], f32x4 a0, f32x4 a1, f32x4 b0, f32x4 b1) {
        const f32x4 xx0 = a0 * a0, xx1 = a1 * a1;
        const f32x4 yy0 = b0 * b0, yy1 = b1 * b1;
        const f32x4 xy0 = a0 * b0, xy1 = a1 * b1;
        F8 fx, fy, fxx, fyy, fxy;
#pragma unroll
        for (int j = 0; j < 4; ++j) {
            fx.b[j]      = (__bf16)a0[j];
            fx.b[4 + j]  = (__bf16)a1[j];
            fy.b[j]      = (__bf16)b0[j];
            fy.b[4 + j]  = (__bf16)b1[j];
            fxx.b[j]     = (__bf16)xx0[j];
            fxx.b[4 + j] = (__bf16)xx1[j];
            fyy.b[j]     = (__bf16)yy0[j];
            fyy.b[4 + j] = (__bf16)yy1[j];
            fxy.b[j]     = (__bf16)xy0[j];
            fxy.b[4 + j] = (__bf16)xy1[j];
        }
        const f32x4 dX  = __builtin_amdgcn_mfma_f32_16x16x32_bf16(fx.v,  wf.v, z, 0, 0, 0);
        const f32x4 dY  = __builtin_amdgcn_mfma_f32_16x16x32_bf16(fy.v,  wf.v, z, 0, 0, 0);
        const f32x4 dXX = __builtin_amdgcn_mfma_f32_16x16x32_bf16(fxx.v, wf.v, z, 0, 0, 0);
        const f32x4 dYY = __builtin_amdgcn_mfma_f32_16x16x32_bf16(fyy.v, wf.v, z, 0, 0, 0);
        const f32x4 dXY = __builtin_amdgcn_mfma_f32_16x16x32_bf16(fxy.v, wf.v, z, 0, 0, 0);
#pragma unroll
        for (int i = 0; i < 4; ++i) {
            hd[0].b[i] = (__bf16)dX[i];
            hd[1].b[i] = (__bf16)dY[i];
            hd[2].b[i] = (__bf16)dXX[i];
            hd[3].b[i] = (__bf16)dYY[i];
            hd[4].b[i] = (__bf16)dXY[i];
        }
    };

    f32x4 vacc = z;                       // packed accumulator (fixed order)
    const int gxv   = gx0 + m;            // this lane's output col
    const bool colok = (gxv < ODIM);

    // V stage + vectorized SSIM epilogue for output tile vt (literal)
    auto vstage = [&](const F4 (&h0)[5], const F4 (&h1)[5], int vt) {
        f32x4 e[5];
#pragma unroll
        for (int q = 0; q < 5; ++q) {
            e[q] = mfma16(wa1, h1[q], z);
            e[q] = mfma16(wa0, h0[q], e[q]);
        }
        const float C1 = 1e-4f, C2 = 9e-4f;
        const f32x4 mX = e[0], mY = e[1];
        const f32x4 muXX = mX * mX;
        const f32x4 muYY = mY * mY;
        const f32x4 muXY = mX * mY;
        const f32x4 sXX = e[2] - muXX;
        const f32x4 sYY = e[3] - muYY;
        const f32x4 sXY = e[4] - muXY;
        const f32x4 num = (2.f * muXY + C1) * (2.f * sXY + C2);
        const f32x4 den = (muXX + muYY + C1) * (sXX + sYY + C2);
        f32x4 val;
#pragma unroll
        for (int i = 0; i < 4; ++i) val[i] = __fdividef(num[i], den[i]);
        const int gyb = gy0 + 16 * vt + 4 * g;   // rows gyb..gyb+3
#pragma unroll
        for (int i = 0; i < 4; ++i)
            vacc[i] += (colok && (gyb + i < ODIM)) ? val[i] : 0.f;
    };

    // ---- live-2 pipeline (round-8 structure): named bufs A/B, h slots A/B --
    f32x4 xA0, xA1, yA0, yA1;    // raw buffer A
    f32x4 xB0, xB1, yB0, yB1;    // raw buffer B
    F4 hA[5], hB[5];

    // tiles 0..7 never clamp (max gy = 384+112+15 = 511); tile 8 clamps.
#define LOADRAW(rt, X0, X1, Y0, Y1) do {                                   \
        const float* xr_;  const float* yr_;                               \
        if ((rt) < 8) {                                                    \
            xr_ = xbase + (rt) * 16 * IMG;                                 \
            yr_ = ybase + (rt) * 16 * IMG;                                 \
        } else {                                                           \
            const int gy_ = min(gy0 + 16 * (rt) + m, IMG - 1);             \
            xr_ = Xp + gy_ * IMG + cs;                                     \
            yr_ = Yp + gy_ * IMG + cs;                                     \
        }                                                                  \
        X0 = *(const f32x4*)xr_;  X1 = *(const f32x4*)(xr_ + 4);           \
        Y0 = *(const f32x4*)yr_;  Y1 = *(const f32x4*)(yr_ + 4);           \
    } while (0)

    LOADRAW(0, xA0, xA1, yA0, yA1);
    LOADRAW(1, xB0, xB1, yB0, yB1);
    mfmaH(hA, xA0, xA1, yA0, yA1);

    // even vt: prefetch into A (its H already consumed), H(B)->hB, V(hA,hB)
#define STEP_E(vt) do {                                         \
        if ((vt) + 2 < NHT) LOADRAW((vt) + 2, xA0, xA1, yA0, yA1); \
        mfmaH(hB, xB0, xB1, yB0, yB1);                          \
        vstage(hA, hB, (vt));                                   \
    } while (0)
    // odd vt: prefetch into B, H(A)->hA, V(hB,hA)
#define STEP_O(vt) do {                                         \
        if ((vt) + 2 < NHT) LOADRAW((vt) + 2, xB0, xB1, yB0, yB1); \
        mfmaH(hA, xA0, xA1, yA0, yA1);                          \
        vstage(hB, hA, (vt));                                   \
    } while (0)

    STEP_E(0); STEP_O(1); STEP_E(2); STEP_O(3);
    STEP_E(4); STEP_O(5); STEP_E(6); STEP_O(7);
#undef STEP_E
#undef STEP_O
#undef LOADRAW

    // ---- deterministic reductions: vec4 -> lane -> wave ----
    float acc = (vacc[0] + vacc[1]) + (vacc[2] + vacc[3]);
#pragma unroll
    for (int off = 32; off > 0; off >>= 1)
        acc += __shfl_down(acc, off, 64);

    if (lane == 0) {
        partial[((size_t)blockIdx.z * gridDim.y + blockIdx.y) * gridDim.x + blockIdx.x] = acc;
    }
}

__global__ __launch_bounds__(512) void ssim_finish_kernel(
    const float* __restrict__ partial, float* __restrict__ out)
{
    __shared__ double sd[512];
    const float4* p4 = (const float4*)partial;   // NBLK = 8192 = 512*4*4
    double local = 0.0;
#pragma unroll
    for (int i = 0; i < 4; ++i) {
        const float4 v = p4[threadIdx.x + 512 * i];
        local += ((double)v.x + (double)v.y) + ((double)v.z + (double)v.w);
    }
    sd[threadIdx.x] = local;
    __syncthreads();
    for (int s = 256; s > 0; s >>= 1) {
        if (threadIdx.x < s) sd[threadIdx.x] += sd[threadIdx.x + s];
        __syncthreads();
    }
    if (threadIdx.x == 0) {
        const double cnt = (double)NC * (double)ODIM * (double)ODIM;
        out[0] = (float)(1.0 - sd[0] / cnt);
    }
}

extern "C" void kernel_launch(void* const* d_in, const int* in_sizes, int n_in,
                              void* d_out, int out_size, void* d_ws, size_t ws_size,
                              hipStream_t stream) {
    const float* X = (const float*)d_in[0];
    const float* Y = (const float*)d_in[1];
    float* out = (float*)d_out;
    float* partial = (float*)d_ws;   // NBLK floats = 32 KiB

    // Gaussian taps in float64 -> f32 (matches numpy reference construction).
    GaussW gw;
    {
        double gd[11], s = 0.0;
        for (int i = 0; i < 11; ++i) {
            const double x = (double)(i - 5);
            gd[i] = std::exp(-(x * x) / (2.0 * 1.5 * 1.5));
            s += gd[i];
        }
        for (int i = 0; i < 11; ++i) gw.g[i] = (float)(gd[i] / s);
    }

    dim3 grid(GX, GY, NC);
    ssim_mfma_kernel<<<grid, 64, 0, stream>>>(X, Y, partial, gw);
    ssim_finish_kernel<<<1, 512, 0, stream>>>(partial, out);
}

// Round 19
// 77.958 us; speedup vs baseline: 2.6756x; 2.0735x over previous
//
#include <hip/hip_runtime.h>
#include <hip/hip_bf16.h>
#include <cmath>

// SSIM loss via MFMA, round 19: 1-wave blocks + live-2 pipeline + LOOSE cap.
// H pass: 16x16x32 bf16 MFMA (A=data rows, B=banded Gaussian W).
// H's D-layout (lane: rows 4g+i, col m) IS the B-frag layout of a K=16 MFMA
// (lane: k=4g+j, col m), so V = 2 chained mfma_16x16x16_bf16 per quantity with
// B-frags straight from H result registers. No hq LDS staging.
// Round-18 post-mortem: (64,8) caps unified regs at 64; gfx950 split it
// 32 VGPR + 32 AGPR -> even live-2 state spilled (VGPR_Count 32 + 224MB
// scratch writes). Round 17/18 DID confirm 1-wave blocks reach ~70% occupancy.
// Fix: __launch_bounds__(64,4) (cap 128) -- compiler allocates its natural
// ~50-70 regs, occupancy then set by ACTUAL allocation (512/regs), not the
// declared bound. First config where fitting pipeline + high TLP coexist.

#define IMG   512
#define ODIM  502            // 512 - 11 + 1
#define SC    16             // strip cols (per wave/block)
#define BR    128            // strip rows
#define GX    32             // 512/16
#define GY    4              // 512/128
#define NC    64             // batch*channels
#define NBLK  (GX * GY * NC) // 8192
#define NVT   8              // V tiles per strip
#define NHT   9              // H tiles per strip

typedef float          f32x4  __attribute__((ext_vector_type(4)));
typedef __bf16         bf16x8 __attribute__((ext_vector_type(8)));
typedef __bf16         bf16x4 __attribute__((ext_vector_type(4)));
typedef short          s16x4  __attribute__((ext_vector_type(4)));
typedef unsigned int   u32x2  __attribute__((ext_vector_type(2)));
typedef unsigned int   u32x4  __attribute__((ext_vector_type(4)));

union F8 { bf16x8 v; __bf16 b[8]; u32x4 q; };
union F4 { bf16x4 v; s16x4 s; __bf16 b[4]; u32x2 q; };

__device__ __forceinline__ unsigned short bfbits(float f) {
    __bf16 h = (__bf16)f;
    return __builtin_bit_cast(unsigned short, h);
}

__device__ __forceinline__ f32x4 mfma16(const F4& a, const F4& b, f32x4 c) {
    return __builtin_amdgcn_mfma_f32_16x16x16bf16_1k(a.s, b.s, c, 0, 0, 0);
}

struct GaussW { float g[11]; };

__global__ __launch_bounds__(64, 4) void ssim_mfma_kernel(
    const float* __restrict__ X, const float* __restrict__ Y,
    float* __restrict__ partial, GaussW gw)
{
    __shared__ unsigned short wl[16][40];   // band weights: wl[m][k] = w[k-m]

    const int lane = threadIdx.x;           // one wave per block
    const int m    = lane & 15;
    const int g    = lane >> 4;

    // ---- weight band LUT (filled by this wave) ----
    for (int t = lane; t < 16 * 40; t += 64) {
        const int mm = t / 40, kk = t - 40 * mm;
        const int d  = kk - mm;
        wl[mm][kk] = bfbits((kk < 32 && d >= 0 && d < 11) ? gw.g[d] : 0.f);
    }
    __syncthreads();                        // wave-local: cheap

    const int gx0 = blockIdx.x * SC;        // this wave's strip
    const int gy0 = blockIdx.y * BR;
    const int nc  = blockIdx.z;
    const float* __restrict__ Xp = X + (size_t)nc * IMG * IMG;
    const float* __restrict__ Yp = Y + (size_t)nc * IMG * IMG;

    F8 wf;  wf.q  = *(const u32x4*)&wl[m][8 * g];       // H B-frag: w[8g+j - m]
    F4 wa0; wa0.q = *(const u32x2*)&wl[m][4 * g];       // V A chunk0: w[4g+j - m]
    F4 wa1; wa1.q = *(const u32x2*)&wl[m][16 + 4 * g];  // V A chunk1: w[16+4g+j - m]
    const f32x4 z = {0.f, 0.f, 0.f, 0.f};

    const int cs = min(gx0 + 8 * g, IMG - 8);   // clamped cols feed only masked
                                                // outputs (band is zero there)
    const float* __restrict__ xbase = Xp + (gy0 + m) * IMG + cs;
    const float* __restrict__ ybase = Yp + (gy0 + m) * IMG + cs;

    // H stage from by-value raw regs; squares via f32x4 vector ops
    auto mfmaH = [&](F4 (&hd)[5], f32x4 a0, f32x4 a1, f32x4 b0, f32x4 b1) {
        const f32x4 xx0 = a0 * a0, xx1 = a1 * a1;
        const f32x4 yy0 = b0 * b0, yy1 = b1 * b1;
        const f32x4 xy0 = a0 * b0, xy1 = a1 * b1;
        F8 fx, fy, fxx, fyy, fxy;
#pragma unroll
        for (int j = 0; j < 4; ++j) {
            fx.b[j]      = (__bf16)a0[j];
            fx.b[4 + j]  = (__bf16)a1[j];
            fy.b[j]      = (__bf16)b0[j];
            fy.b[4 + j]  = (__bf16)b1[j];
            fxx.b[j]     = (__bf16)xx0[j];
            fxx.b[4 + j] = (__bf16)xx1[j];
            fyy.b[j]     = (__bf16)yy0[j];
            fyy.b[4 + j] = (__bf16)yy1[j];
            fxy.b[j]     = (__bf16)xy0[j];
            fxy.b[4 + j] = (__bf16)xy1[j];
        }
        const f32x4 dX  = __builtin_amdgcn_mfma_f32_16x16x32_bf16(fx.v,  wf.v, z, 0, 0, 0);
        const f32x4 dY  = __builtin_amdgcn_mfma_f32_16x16x32_bf16(fy.v,  wf.v, z, 0, 0, 0);
        const f32x4 dXX = __builtin_amdgcn_mfma_f32_16x16x32_bf16(fxx.v, wf.v, z, 0, 0, 0);
        const f32x4 dYY = __builtin_amdgcn_mfma_f32_16x16x32_bf16(fyy.v, wf.v, z, 0, 0, 0);
        const f32x4 dXY = __builtin_amdgcn_mfma_f32_16x16x32_bf16(fxy.v, wf.v, z, 0, 0, 0);
#pragma unroll
        for (int i = 0; i < 4; ++i) {
            hd[0].b[i] = (__bf16)dX[i];
            hd[1].b[i] = (__bf16)dY[i];
            hd[2].b[i] = (__bf16)dXX[i];
            hd[3].b[i] = (__bf16)dYY[i];
            hd[4].b[i] = (__bf16)dXY[i];
        }
    };

    f32x4 vacc = z;                       // packed accumulator (fixed order)
    const int gxv   = gx0 + m;            // this lane's output col
    const bool colok = (gxv < ODIM);

    // V stage + vectorized SSIM epilogue for output tile vt (literal)
    auto vstage = [&](const F4 (&h0)[5], const F4 (&h1)[5], int vt) {
        f32x4 e[5];
#pragma unroll
        for (int q = 0; q < 5; ++q) {
            e[q] = mfma16(wa1, h1[q], z);
            e[q] = mfma16(wa0, h0[q], e[q]);
        }
        const float C1 = 1e-4f, C2 = 9e-4f;
        const f32x4 mX = e[0], mY = e[1];
        const f32x4 muXX = mX * mX;
        const f32x4 muYY = mY * mY;
        const f32x4 muXY = mX * mY;
        const f32x4 sXX = e[2] - muXX;
        const f32x4 sYY = e[3] - muYY;
        const f32x4 sXY = e[4] - muXY;
        const f32x4 num = (2.f * muXY + C1) * (2.f * sXY + C2);
        const f32x4 den = (muXX + muYY + C1) * (sXX + sYY + C2);
        f32x4 val;
#pragma unroll
        for (int i = 0; i < 4; ++i) val[i] = __fdividef(num[i], den[i]);
        const int gyb = gy0 + 16 * vt + 4 * g;   // rows gyb..gyb+3
#pragma unroll
        for (int i = 0; i < 4; ++i)
            vacc[i] += (colok && (gyb + i < ODIM)) ? val[i] : 0.f;
    };

    // ---- live-2 pipeline (round-8 structure): named bufs A/B, h slots A/B --
    f32x4 xA0, xA1, yA0, yA1;    // raw buffer A
    f32x4 xB0, xB1, yB0, yB1;    // raw buffer B
    F4 hA[5], hB[5];

    // tiles 0..7 never clamp (max gy = 384+112+15 = 511); tile 8 clamps.
#define LOADRAW(rt, X0, X1, Y0, Y1) do {                                   \
        const float* xr_;  const float* yr_;                               \
        if ((rt) < 8) {                                                    \
            xr_ = xbase + (rt) * 16 * IMG;                                 \
            yr_ = ybase + (rt) * 16 * IMG;                                 \
        } else {                                                           \
            const int gy_ = min(gy0 + 16 * (rt) + m, IMG - 1);             \
            xr_ = Xp + gy_ * IMG + cs;                                     \
            yr_ = Yp + gy_ * IMG + cs;                                     \
        }                                                                  \
        X0 = *(const f32x4*)xr_;  X1 = *(const f32x4*)(xr_ + 4);           \
        Y0 = *(const f32x4*)yr_;  Y1 = *(const f32x4*)(yr_ + 4);           \
    } while (0)

    LOADRAW(0, xA0, xA1, yA0, yA1);
    LOADRAW(1, xB0, xB1, yB0, yB1);
    mfmaH(hA, xA0, xA1, yA0, yA1);

    // even vt: prefetch into A (its H already consumed), H(B)->hB, V(hA,hB)
#define STEP_E(vt) do {                                         \
        if ((vt) + 2 < NHT) LOADRAW((vt) + 2, xA0, xA1, yA0, yA1); \
        mfmaH(hB, xB0, xB1, yB0, yB1);                          \
        vstage(hA, hB, (vt));                                   \
    } while (0)
    // odd vt: prefetch into B, H(A)->hA, V(hB,hA)
#define STEP_O(vt) do {                                         \
        if ((vt) + 2 < NHT) LOADRAW((vt) + 2, xB0, xB1, yB0, yB1); \
        mfmaH(hA, xA0, xA1, yA0, yA1);                          \
        vstage(hB, hA, (vt));                                   \
    } while (0)

    STEP_E(0); STEP_O(1); STEP_E(2); STEP_O(3);
    STEP_E(4); STEP_O(5); STEP_E(6); STEP_O(7);
#undef STEP_E
#undef STEP_O
#undef LOADRAW

    // ---- deterministic reductions: vec4 -> lane -> wave ----
    float acc = (vacc[0] + vacc[1]) + (vacc[2] + vacc[3]);
#pragma unroll
    for (int off = 32; off > 0; off >>= 1)
        acc += __shfl_down(acc, off, 64);

    if (lane == 0) {
        partial[((size_t)blockIdx.z * gridDim.y + blockIdx.y) * gridDim.x + blockIdx.x] = acc;
    }
}

__global__ __launch_bounds__(512) void ssim_finish_kernel(
    const float* __restrict__ partial, float* __restrict__ out)
{
    __shared__ double sd[512];
    const float4* p4 = (const float4*)partial;   // NBLK = 8192 = 512*4*4
    double local = 0.0;
#pragma unroll
    for (int i = 0; i < 4; ++i) {
        const float4 v = p4[threadIdx.x + 512 * i];
        local += ((double)v.x + (double)v.y) + ((double)v.z + (double)v.w);
    }
    sd[threadIdx.x] = local;
    __syncthreads();
    for (int s = 256; s > 0; s >>= 1) {
        if (threadIdx.x < s) sd[threadIdx.x] += sd[threadIdx.x + s];
        __syncthreads();
    }
    if (threadIdx.x == 0) {
        const double cnt = (double)NC * (double)ODIM * (double)ODIM;
        out[0] = (float)(1.0 - sd[0] / cnt);
    }
}

extern "C" void kernel_launch(void* const* d_in, const int* in_sizes, int n_in,
                              void* d_out, int out_size, void* d_ws, size_t ws_size,
                              hipStream_t stream) {
    const float* X = (const float*)d_in[0];
    const float* Y = (const float*)d_in[1];
    float* out = (float*)d_out;
    float* partial = (float*)d_ws;   // NBLK floats = 32 KiB

    // Gaussian taps in float64 -> f32 (matches numpy reference construction).
    GaussW gw;
    {
        double gd[11], s = 0.0;
        for (int i = 0; i < 11; ++i) {
            const double x = (double)(i - 5);
            gd[i] = std::exp(-(x * x) / (2.0 * 1.5 * 1.5));
            s += gd[i];
        }
        for (int i = 0; i < 11; ++i) gw.g[i] = (float)(gd[i] / s);
    }

    dim3 grid(GX, GY, NC);
    ssim_mfma_kernel<<<grid, 64, 0, stream>>>(X, Y, partial, gw);
    ssim_finish_kernel<<<1, 512, 0, stream>>>(partial, out);
}

// Round 20
// 50.739 us; speedup vs baseline: 4.1109x; 1.5364x over previous
//
#include <hip/hip_runtime.h>
#include <hip/hip_bf16.h>
#include <cmath>

// SSIM loss via MFMA, round 20: 2x the waves (64-row strips), 256-thr blocks.
// H pass: 16x16x32 bf16 MFMA (A=data rows, B=banded Gaussian W).
// H's D-layout (lane: rows 4g+i, col m) IS the B-frag layout of a K=16 MFMA
// (lane: k=4g+j, col m), so V = 2 chained mfma_16x16x16_bf16 per quantity with
// B-frags straight from H result registers. No hq LDS, no mid-kernel barrier.
// Round-19 lessons: 16-col strips double HBM fetch (64B rows, cross-XCD line
// splits) -> keep 64-col blocks (256B rows). Round 13-14 arithmetic: grid
// supplied exactly 8 waves/SIMD and issue util == 47% == 8 x per-wave issue /
// lifetime -> GRID-capped TLP. Fix: BR 128->64 (GY=8) => 16384 waves
// (16/SIMD available); residency now set by VGPR (~8-10/SIMD), not the grid.
// Pipeline = round 13's 3-phase rotation trimmed to 5 H / 4 V tiles.

#define IMG   512
#define ODIM  502            // 512 - 11 + 1
#define SC    16             // strip cols (per wave)
#define BR    64             // strip rows
#define WPB   4              // waves per block
#define BC    (SC * WPB)     // 64 block cols (256B rows -> clean fetch)
#define GX    8              // 512/64
#define GY    8              // 512/64
#define NC    64             // batch*channels
#define NBLK  (GX * GY * NC) // 4096
#define NVT   4              // V tiles per strip (4*16 = 64 rows)
#define NHT   5              // H tiles per strip

typedef float          f32x4  __attribute__((ext_vector_type(4)));
typedef __bf16         bf16x8 __attribute__((ext_vector_type(8)));
typedef __bf16         bf16x4 __attribute__((ext_vector_type(4)));
typedef short          s16x4  __attribute__((ext_vector_type(4)));
typedef unsigned int   u32x2  __attribute__((ext_vector_type(2)));
typedef unsigned int   u32x4  __attribute__((ext_vector_type(4)));

union F8 { bf16x8 v; __bf16 b[8]; u32x4 q; };
union F4 { bf16x4 v; s16x4 s; __bf16 b[4]; u32x2 q; };

__device__ __forceinline__ unsigned short bfbits(float f) {
    __bf16 h = (__bf16)f;
    return __builtin_bit_cast(unsigned short, h);
}

__device__ __forceinline__ f32x4 mfma16(const F4& a, const F4& b, f32x4 c) {
    return __builtin_amdgcn_mfma_f32_16x16x16bf16_1k(a.s, b.s, c, 0, 0, 0);
}

struct GaussW { float g[11]; };

__global__ __launch_bounds__(256, 4) void ssim_mfma_kernel(
    const float* __restrict__ X, const float* __restrict__ Y,
    float* __restrict__ partial, GaussW gw)
{
    __shared__ unsigned short wl[16][40];   // band weights: wl[m][k] = w[k-m]
    __shared__ float wsum[WPB];

    const int tid  = threadIdx.x;
    const int lane = tid & 63;
    const int wave = tid >> 6;
    const int m    = lane & 15;
    const int g    = lane >> 4;

    // ---- weight band LUT (1.25 KB, filled once) ----
    for (int t = tid; t < 16 * 40; t += 256) {
        const int mm = t / 40, kk = t - 40 * mm;
        const int d  = kk - mm;
        wl[mm][kk] = bfbits((kk < 32 && d >= 0 && d < 11) ? gw.g[d] : 0.f);
    }
    __syncthreads();

    const int gx0 = blockIdx.x * BC + SC * wave;   // this wave's strip
    const int gy0 = blockIdx.y * BR;
    const int nc  = blockIdx.z;
    const float* __restrict__ Xp = X + (size_t)nc * IMG * IMG;
    const float* __restrict__ Yp = Y + (size_t)nc * IMG * IMG;

    F8 wf;  wf.q  = *(const u32x4*)&wl[m][8 * g];       // H B-frag: w[8g+j - m]
    F4 wa0; wa0.q = *(const u32x2*)&wl[m][4 * g];       // V A chunk0: w[4g+j - m]
    F4 wa1; wa1.q = *(const u32x2*)&wl[m][16 + 4 * g];  // V A chunk1: w[16+4g+j - m]
    const f32x4 z = {0.f, 0.f, 0.f, 0.f};

    const int cs = min(gx0 + 8 * g, IMG - 8);   // clamped cols feed only masked
                                                // outputs (band is zero there)
    const float* __restrict__ xbase = Xp + (gy0 + m) * IMG + cs;
    const float* __restrict__ ybase = Yp + (gy0 + m) * IMG + cs;

    // H stage from by-value raw regs; squares via f32x4 vector ops (pk_mul)
    auto mfmaH = [&](F4 (&hd)[5], f32x4 a0, f32x4 a1, f32x4 b0, f32x4 b1) {
        const f32x4 xx0 = a0 * a0, xx1 = a1 * a1;
        const f32x4 yy0 = b0 * b0, yy1 = b1 * b1;
        const f32x4 xy0 = a0 * b0, xy1 = a1 * b1;
        F8 fx, fy, fxx, fyy, fxy;
#pragma unroll
        for (int j = 0; j < 4; ++j) {
            fx.b[j]      = (__bf16)a0[j];
            fx.b[4 + j]  = (__bf16)a1[j];
            fy.b[j]      = (__bf16)b0[j];
            fy.b[4 + j]  = (__bf16)b1[j];
            fxx.b[j]     = (__bf16)xx0[j];
            fxx.b[4 + j] = (__bf16)xx1[j];
            fyy.b[j]     = (__bf16)yy0[j];
            fyy.b[4 + j] = (__bf16)yy1[j];
            fxy.b[j]     = (__bf16)xy0[j];
            fxy.b[4 + j] = (__bf16)xy1[j];
        }
        const f32x4 dX  = __builtin_amdgcn_mfma_f32_16x16x32_bf16(fx.v,  wf.v, z, 0, 0, 0);
        const f32x4 dY  = __builtin_amdgcn_mfma_f32_16x16x32_bf16(fy.v,  wf.v, z, 0, 0, 0);
        const f32x4 dXX = __builtin_amdgcn_mfma_f32_16x16x32_bf16(fxx.v, wf.v, z, 0, 0, 0);
        const f32x4 dYY = __builtin_amdgcn_mfma_f32_16x16x32_bf16(fyy.v, wf.v, z, 0, 0, 0);
        const f32x4 dXY = __builtin_amdgcn_mfma_f32_16x16x32_bf16(fxy.v, wf.v, z, 0, 0, 0);
#pragma unroll
        for (int i = 0; i < 4; ++i) {
            hd[0].b[i] = (__bf16)dX[i];
            hd[1].b[i] = (__bf16)dY[i];
            hd[2].b[i] = (__bf16)dXX[i];
            hd[3].b[i] = (__bf16)dYY[i];
            hd[4].b[i] = (__bf16)dXY[i];
        }
    };

    f32x4 vacc = z;                       // packed accumulator (fixed order)
    const int gxv   = gx0 + m;            // this lane's output col
    const bool colok = (gxv < ODIM);

    // V stage + vectorized SSIM epilogue for output tile vt (literal)
    auto vstage = [&](const F4 (&h0)[5], const F4 (&h1)[5], int vt) {
        f32x4 e[5];
#pragma unroll
        for (int q = 0; q < 5; ++q) {
            e[q] = mfma16(wa1, h1[q], z);
            e[q] = mfma16(wa0, h0[q], e[q]);
        }
        const float C1 = 1e-4f, C2 = 9e-4f;
        const f32x4 mX = e[0], mY = e[1];
        const f32x4 muXX = mX * mX;
        const f32x4 muYY = mY * mY;
        const f32x4 muXY = mX * mY;
        const f32x4 sXX = e[2] - muXX;
        const f32x4 sYY = e[3] - muYY;
        const f32x4 sXY = e[4] - muXY;
        const f32x4 num = (2.f * muXY + C1) * (2.f * sXY + C2);
        const f32x4 den = (muXX + muYY + C1) * (sXX + sYY + C2);
        f32x4 val;
#pragma unroll
        for (int i = 0; i < 4; ++i) val[i] = __fdividef(num[i], den[i]);
        const int gyb = gy0 + 16 * vt + 4 * g;   // rows gyb..gyb+3
#pragma unroll
        for (int i = 0; i < 4; ++i)
            vacc[i] += (colok && (gyb + i < ODIM)) ? val[i] : 0.f;
    };

    // ---- 3-phase pipeline: named raw trios A/B/C, h slots h0/h1/h2 ----
    f32x4 xA0, xA1, yA0, yA1;
    f32x4 xB0, xB1, yB0, yB1;
    f32x4 xC0, xC1, yC0, yC1;
    F4 h0[5], h1[5], h2[5];

    // tiles 0..3 never clamp (max gy = 448+48+15 = 511); tile 4 clamps.
#define LOADRAW(rt, X0, X1, Y0, Y1) do {                                   \
        const float* xr_;  const float* yr_;                               \
        if ((rt) < 4) {                                                    \
            xr_ = xbase + (rt) * 16 * IMG;                                 \
            yr_ = ybase + (rt) * 16 * IMG;                                 \
        } else {                                                           \
            const int gy_ = min(gy0 + 16 * (rt) + m, IMG - 1);             \
            xr_ = Xp + gy_ * IMG + cs;                                     \
            yr_ = Yp + gy_ * IMG + cs;                                     \
        }                                                                  \
        X0 = *(const f32x4*)xr_;  X1 = *(const f32x4*)(xr_ + 4);           \
        Y0 = *(const f32x4*)yr_;  Y1 = *(const f32x4*)(yr_ + 4);           \
    } while (0)

    // prologue: 3 tile-loads in flight, then H(0), H(1)
    LOADRAW(0, xA0, xA1, yA0, yA1);
    LOADRAW(1, xB0, xB1, yB0, yB1);
    LOADRAW(2, xC0, xC1, yC0, yC1);
    mfmaH(h0, xA0, xA1, yA0, yA1);          // tile 0 -> slot 0
    mfmaH(h1, xB0, xB1, yB0, yB1);          // tile 1 -> slot 1

    // step t: L(t+3) | H(t+2) | V(t).  tile k lives in raw/h slot k%3.
    LOADRAW(3, xA0, xA1, yA0, yA1);  mfmaH(h2, xC0, xC1, yC0, yC1);  vstage(h0, h1, 0);
    LOADRAW(4, xB0, xB1, yB0, yB1);  mfmaH(h0, xA0, xA1, yA0, yA1);  vstage(h1, h2, 1);
                                     mfmaH(h1, xB0, xB1, yB0, yB1);  vstage(h2, h0, 2);
                                                                     vstage(h0, h1, 3);
#undef LOADRAW

    // ---- deterministic reductions: vec4 -> lane -> wave -> block ----
    float acc = (vacc[0] + vacc[1]) + (vacc[2] + vacc[3]);
#pragma unroll
    for (int off = 32; off > 0; off >>= 1)
        acc += __shfl_down(acc, off, 64);

    if (lane == 0) wsum[wave] = acc;
    __syncthreads();
    if (tid == 0) {
        const float tsum = (wsum[0] + wsum[1]) + (wsum[2] + wsum[3]);
        partial[((size_t)blockIdx.z * gridDim.y + blockIdx.y) * gridDim.x + blockIdx.x] = tsum;
    }
}

__global__ __launch_bounds__(512) void ssim_finish_kernel(
    const float* __restrict__ partial, float* __restrict__ out)
{
    __shared__ double sd[512];
    const float4* p4 = (const float4*)partial;   // NBLK = 4096 = 512*2*4
    double local = 0.0;
#pragma unroll
    for (int i = 0; i < 2; ++i) {
        const float4 v = p4[threadIdx.x + 512 * i];
        local += ((double)v.x + (double)v.y) + ((double)v.z + (double)v.w);
    }
    sd[threadIdx.x] = local;
    __syncthreads();
    for (int s = 256; s > 0; s >>= 1) {
        if (threadIdx.x < s) sd[threadIdx.x] += sd[threadIdx.x + s];
        __syncthreads();
    }
    if (threadIdx.x == 0) {
        const double cnt = (double)NC * (double)ODIM * (double)ODIM;
        out[0] = (float)(1.0 - sd[0] / cnt);
    }
}

extern "C" void kernel_launch(void* const* d_in, const int* in_sizes, int n_in,
                              void* d_out, int out_size, void* d_ws, size_t ws_size,
                              hipStream_t stream) {
    const float* X = (const float*)d_in[0];
    const float* Y = (const float*)d_in[1];
    float* out = (float*)d_out;
    float* partial = (float*)d_ws;   // NBLK floats = 16 KiB

    // Gaussian taps in float64 -> f32 (matches numpy reference construction).
    GaussW gw;
    {
        double gd[11], s = 0.0;
        for (int i = 0; i < 11; ++i) {
            const double x = (double)(i - 5);
            gd[i] = std::exp(-(x * x) / (2.0 * 1.5 * 1.5));
            s += gd[i];
        }
        for (int i = 0; i < 11; ++i) gw.g[i] = (float)(gd[i] / s);
    }

    dim3 grid(GX, GY, NC);
    ssim_mfma_kernel<<<grid, 256, 0, stream>>>(X, Y, partial, gw);
    ssim_finish_kernel<<<1, 512, 0, stream>>>(partial, out);
}

// Round 21
// 45.251 us; speedup vs baseline: 4.6095x; 1.1213x over previous
//
#include <hip/hip_runtime.h>
#include <hip/hip_bf16.h>
#include <cmath>

// SSIM loss via MFMA, round 21: 4-conv S/D algebra on round-13 structure.
// Key algebra: SSIM needs only {muX, muY, sigmaXY, sigmaX^2+sigmaY^2}.
// With S=X+Y, D=X-Y:  muX*muY=(muS^2-muD^2)/4, muX^2+muY^2=(muS^2+muD^2)/2,
// E[XY]=(E[S^2]-E[D^2])/4, E[X^2]+E[Y^2]=(E[S^2]+E[D^2])/2.
// => FOUR convolved quantities (S, D, S^2, D^2) instead of five:
// 20% fewer H/V MFMAs, cvt/pack ops, h registers, and a 20% shorter
// per-step dependency chain. Epilogue re-derived below.
// H pass: 16x16x32 bf16 MFMA (A=data rows, B=banded Gaussian W); H's D-layout
// IS the B-frag layout of a K=16 MFMA, so V = 2 chained mfma_16x16x16_bf16
// per quantity from registers. No hq LDS, no mid-kernel barrier (round 13).

#define IMG   512
#define ODIM  502            // 512 - 11 + 1
#define SC    16             // strip cols (per wave)
#define BR    128            // strip rows
#define WPB   4              // waves per block
#define BC    (SC * WPB)     // 64 block cols
#define GX    8              // 512/64
#define GY    4              // 512/128
#define NC    64             // batch*channels
#define NBLK  (GX * GY * NC) // 2048
#define NVT   8              // V tiles per strip
#define NHT   9              // H tiles per strip

typedef float          f32x4  __attribute__((ext_vector_type(4)));
typedef __bf16         bf16x8 __attribute__((ext_vector_type(8)));
typedef __bf16         bf16x4 __attribute__((ext_vector_type(4)));
typedef short          s16x4  __attribute__((ext_vector_type(4)));
typedef unsigned int   u32x2  __attribute__((ext_vector_type(2)));
typedef unsigned int   u32x4  __attribute__((ext_vector_type(4)));

union F8 { bf16x8 v; __bf16 b[8]; u32x4 q; };
union F4 { bf16x4 v; s16x4 s; __bf16 b[4]; u32x2 q; };

__device__ __forceinline__ unsigned short bfbits(float f) {
    __bf16 h = (__bf16)f;
    return __builtin_bit_cast(unsigned short, h);
}

__device__ __forceinline__ f32x4 mfma16(const F4& a, const F4& b, f32x4 c) {
    return __builtin_amdgcn_mfma_f32_16x16x16bf16_1k(a.s, b.s, c, 0, 0, 0);
}

struct GaussW { float g[11]; };

__global__ __launch_bounds__(256, 4) void ssim_mfma_kernel(
    const float* __restrict__ X, const float* __restrict__ Y,
    float* __restrict__ partial, GaussW gw)
{
    __shared__ unsigned short wl[16][40];   // band weights: wl[m][k] = w[k-m]
    __shared__ float wsum[WPB];

    const int tid  = threadIdx.x;
    const int lane = tid & 63;
    const int wave = tid >> 6;
    const int m    = lane & 15;
    const int g    = lane >> 4;

    // ---- weight band LUT (1.25 KB, filled once) ----
    for (int t = tid; t < 16 * 40; t += 256) {
        const int mm = t / 40, kk = t - 40 * mm;
        const int d  = kk - mm;
        wl[mm][kk] = bfbits((kk < 32 && d >= 0 && d < 11) ? gw.g[d] : 0.f);
    }
    __syncthreads();

    const int gx0 = blockIdx.x * BC + SC * wave;   // this wave's strip
    const int gy0 = blockIdx.y * BR;
    const int nc  = blockIdx.z;
    const float* __restrict__ Xp = X + (size_t)nc * IMG * IMG;
    const float* __restrict__ Yp = Y + (size_t)nc * IMG * IMG;

    F8 wf;  wf.q  = *(const u32x4*)&wl[m][8 * g];       // H B-frag: w[8g+j - m]
    F4 wa0; wa0.q = *(const u32x2*)&wl[m][4 * g];       // V A chunk0: w[4g+j - m]
    F4 wa1; wa1.q = *(const u32x2*)&wl[m][16 + 4 * g];  // V A chunk1: w[16+4g+j - m]
    const f32x4 z = {0.f, 0.f, 0.f, 0.f};

    const int cs = min(gx0 + 8 * g, IMG - 8);   // clamped cols feed only masked
                                                // outputs (band is zero there)
    const float* __restrict__ xbase = Xp + (gy0 + m) * IMG + cs;
    const float* __restrict__ ybase = Yp + (gy0 + m) * IMG + cs;

    // H stage: quantities S=X+Y, D=X-Y, S^2, D^2 (4 MFMAs, was 5)
    auto mfmaH = [&](F4 (&hd)[4], f32x4 a0, f32x4 a1, f32x4 b0, f32x4 b1) {
        const f32x4 S0 = a0 + b0, S1 = a1 + b1;
        const f32x4 D0 = a0 - b0, D1 = a1 - b1;
        const f32x4 SS0 = S0 * S0, SS1 = S1 * S1;
        const f32x4 DD0 = D0 * D0, DD1 = D1 * D1;
        F8 fS, fD, fSS, fDD;
#pragma unroll
        for (int j = 0; j < 4; ++j) {
            fS.b[j]      = (__bf16)S0[j];
            fS.b[4 + j]  = (__bf16)S1[j];
            fD.b[j]      = (__bf16)D0[j];
            fD.b[4 + j]  = (__bf16)D1[j];
            fSS.b[j]     = (__bf16)SS0[j];
            fSS.b[4 + j] = (__bf16)SS1[j];
            fDD.b[j]     = (__bf16)DD0[j];
            fDD.b[4 + j] = (__bf16)DD1[j];
        }
        const f32x4 dS  = __builtin_amdgcn_mfma_f32_16x16x32_bf16(fS.v,  wf.v, z, 0, 0, 0);
        const f32x4 dD  = __builtin_amdgcn_mfma_f32_16x16x32_bf16(fD.v,  wf.v, z, 0, 0, 0);
        const f32x4 dSS = __builtin_amdgcn_mfma_f32_16x16x32_bf16(fSS.v, wf.v, z, 0, 0, 0);
        const f32x4 dDD = __builtin_amdgcn_mfma_f32_16x16x32_bf16(fDD.v, wf.v, z, 0, 0, 0);
#pragma unroll
        for (int i = 0; i < 4; ++i) {
            hd[0].b[i] = (__bf16)dS[i];
            hd[1].b[i] = (__bf16)dD[i];
            hd[2].b[i] = (__bf16)dSS[i];
            hd[3].b[i] = (__bf16)dDD[i];
        }
    };

    f32x4 vacc = z;                       // packed accumulator (fixed order)
    const int gxv   = gx0 + m;            // this lane's output col
    const bool colok = (gxv < ODIM);

    // V stage + S/D SSIM epilogue for output tile vt (literal)
    auto vstage = [&](const F4 (&h0)[4], const F4 (&h1)[4], int vt) {
        f32x4 e[4];
#pragma unroll
        for (int q = 0; q < 4; ++q) {
            e[q] = mfma16(wa1, h1[q], z);
            e[q] = mfma16(wa0, h0[q], e[q]);
        }
        const float C1 = 1e-4f, C2 = 9e-4f;
        const f32x4 muS = e[0], muD = e[1], ES2 = e[2], ED2 = e[3];
        const f32x4 PS = muS * muS;
        const f32x4 PD = muD * muD;
        const f32x4 dP = PS - PD;          // 4*muX*muY
        const f32x4 sP = PS + PD;          // 2*(muX^2+muY^2)
        const f32x4 dE = ES2 - ED2;        // 4*E[XY]
        const f32x4 sE = ES2 + ED2;        // 2*(E[X^2]+E[Y^2])
        const f32x4 num1 = 0.5f * dP + C1;         // 2*muXY + C1
        const f32x4 num2 = 0.5f * (dE - dP) + C2;  // 2*sigmaXY + C2
        const f32x4 den1 = 0.5f * sP + C1;         // muX^2+muY^2 + C1
        const f32x4 den2 = 0.5f * (sE - sP) + C2;  // sigX^2+sigY^2 + C2
        const f32x4 num = num1 * num2;
        const f32x4 den = den1 * den2;
        f32x4 val;
#pragma unroll
        for (int i = 0; i < 4; ++i) val[i] = __fdividef(num[i], den[i]);
        const int gyb = gy0 + 16 * vt + 4 * g;   // rows gyb..gyb+3
#pragma unroll
        for (int i = 0; i < 4; ++i)
            vacc[i] += (colok && (gyb + i < ODIM)) ? val[i] : 0.f;
    };

    // ---- 3-phase pipeline: named raw trios A/B/C, h slots h0/h1/h2 ----
    f32x4 xA0, xA1, yA0, yA1;
    f32x4 xB0, xB1, yB0, yB1;
    f32x4 xC0, xC1, yC0, yC1;
    F4 h0[4], h1[4], h2[4];

    // tiles 0..7 never clamp (max gy = 384+112+15 = 511); tile 8 clamps.
#define LOADRAW(rt, X0, X1, Y0, Y1) do {                                   \
        const float* xr_;  const float* yr_;                               \
        if ((rt) < 8) {                                                    \
            xr_ = xbase + (rt) * 16 * IMG;                                 \
            yr_ = ybase + (rt) * 16 * IMG;                                 \
        } else {                                                           \
            const int gy_ = min(gy0 + 16 * (rt) + m, IMG - 1);             \
            xr_ = Xp + gy_ * IMG + cs;                                     \
            yr_ = Yp + gy_ * IMG + cs;                                     \
        }                                                                  \
        X0 = *(const f32x4*)xr_;  X1 = *(const f32x4*)(xr_ + 4);           \
        Y0 = *(const f32x4*)yr_;  Y1 = *(const f32x4*)(yr_ + 4);           \
    } while (0)

    // prologue: 3 tile-loads in flight, then H(0), H(1)
    LOADRAW(0, xA0, xA1, yA0, yA1);
    LOADRAW(1, xB0, xB1, yB0, yB1);
    LOADRAW(2, xC0, xC1, yC0, yC1);
    mfmaH(h0, xA0, xA1, yA0, yA1);          // tile 0 -> slot 0
    mfmaH(h1, xB0, xB1, yB0, yB1);          // tile 1 -> slot 1

    // step t: L(t+3) | H(t+2) | V(t).  tile k lives in raw/h slot k%3.
    LOADRAW(3, xA0, xA1, yA0, yA1);  mfmaH(h2, xC0, xC1, yC0, yC1);  vstage(h0, h1, 0);
    LOADRAW(4, xB0, xB1, yB0, yB1);  mfmaH(h0, xA0, xA1, yA0, yA1);  vstage(h1, h2, 1);
    LOADRAW(5, xC0, xC1, yC0, yC1);  mfmaH(h1, xB0, xB1, yB0, yB1);  vstage(h2, h0, 2);
    LOADRAW(6, xA0, xA1, yA0, yA1);  mfmaH(h2, xC0, xC1, yC0, yC1);  vstage(h0, h1, 3);
    LOADRAW(7, xB0, xB1, yB0, yB1);  mfmaH(h0, xA0, xA1, yA0, yA1);  vstage(h1, h2, 4);
    LOADRAW(8, xC0, xC1, yC0, yC1);  mfmaH(h1, xB0, xB1, yB0, yB1);  vstage(h2, h0, 5);
                                     mfmaH(h2, xC0, xC1, yC0, yC1);  vstage(h0, h1, 6);
                                                                     vstage(h1, h2, 7);
#undef LOADRAW

    // ---- deterministic reductions: vec4 -> lane -> wave -> block ----
    float acc = (vacc[0] + vacc[1]) + (vacc[2] + vacc[3]);
#pragma unroll
    for (int off = 32; off > 0; off >>= 1)
        acc += __shfl_down(acc, off, 64);

    if (lane == 0) wsum[wave] = acc;
    __syncthreads();
    if (tid == 0) {
        const float tsum = (wsum[0] + wsum[1]) + (wsum[2] + wsum[3]);
        partial[((size_t)blockIdx.z * gridDim.y + blockIdx.y) * gridDim.x + blockIdx.x] = tsum;
    }
}

__global__ __launch_bounds__(512) void ssim_finish_kernel(
    const float* __restrict__ partial, float* __restrict__ out)
{
    __shared__ double sd[512];
    const float4* p4 = (const float4*)partial;   // NBLK = 2048 = 512*4
    const float4 v = p4[threadIdx.x];
    double local = ((double)v.x + (double)v.y) + ((double)v.z + (double)v.w);
    sd[threadIdx.x] = local;
    __syncthreads();
    for (int s = 256; s > 0; s >>= 1) {
        if (threadIdx.x < s) sd[threadIdx.x] += sd[threadIdx.x + s];
        __syncthreads();
    }
    if (threadIdx.x == 0) {
        const double cnt = (double)NC * (double)ODIM * (double)ODIM;
        out[0] = (float)(1.0 - sd[0] / cnt);
    }
}

extern "C" void kernel_launch(void* const* d_in, const int* in_sizes, int n_in,
                              void* d_out, int out_size, void* d_ws, size_t ws_size,
                              hipStream_t stream) {
    const float* X = (const float*)d_in[0];
    const float* Y = (const float*)d_in[1];
    float* out = (float*)d_out;
    float* partial = (float*)d_ws;   // NBLK floats = 8 KiB

    // Gaussian taps in float64 -> f32 (matches numpy reference construction).
    GaussW gw;
    {
        double gd[11], s = 0.0;
        for (int i = 0; i < 11; ++i) {
            const double x = (double)(i - 5);
            gd[i] = std::exp(-(x * x) / (2.0 * 1.5 * 1.5));
            s += gd[i];
        }
        for (int i = 0; i < 11; ++i) gw.g[i] = (float)(gd[i] / s);
    }

    dim3 grid(GX, GY, NC);
    ssim_mfma_kernel<<<grid, 256, 0, stream>>>(X, Y, partial, gw);
    ssim_finish_kernel<<<1, 512, 0, stream>>>(partial, out);
}